// Round 2
// baseline (1788.701 us; speedup 1.0000x reference)
//
#include <hip/hip_runtime.h>

using u32 = unsigned int;

// ---------------- build x0 = [pos, x], padded to 8 cols ----------------
__global__ void k_build_x0(const float* __restrict__ x, const float* __restrict__ pos,
                           float* __restrict__ x0) {
  int p = blockIdx.x * 256 + threadIdx.x;   // 16384 points
  float* o = x0 + (size_t)p * 8;
  o[0] = pos[p*3+0]; o[1] = pos[p*3+1]; o[2] = pos[p*3+2];
  o[3] = x[p*3+0];   o[4] = x[p*3+1];   o[5] = x[p*3+2];
  o[6] = 0.f; o[7] = 0.f;
}

// ---------------- squared norms, wave per point ----------------
__global__ void k_sqnorm(const float* __restrict__ x, int stride, int F,
                         float* __restrict__ sq) {
  int wid  = (blockIdx.x * 256 + threadIdx.x) >> 6;
  int lane = threadIdx.x & 63;
  float v = (lane < F) ? x[(size_t)wid * stride + lane] : 0.f;
  float s = v * v;
  #pragma unroll
  for (int m = 32; m; m >>= 1) s += __shfl_xor(s, m);
  if (lane == 0) sq[wid] = s;
}

// ---------------- distance GEMM: D = sq_i + sq_j - 2 * Xi . Xj ----------------
// grid (16 j-tiles, 4 i-tiles, 8 batches), block 256, 128x128 tile, 8x8/thread
template<int F>
__global__ __launch_bounds__(256) void k_dist(const float* __restrict__ x, int stride,
    const float* __restrict__ sq, int cbase, float* __restrict__ D) {
  constexpr int PAD = F + 4;
  __shared__ __align__(16) float Xi[128 * PAD];
  __shared__ __align__(16) float Xj[128 * PAD];
  __shared__ float SQI[128], SQJ[128];
  int b  = blockIdx.z;
  int i0 = cbase + blockIdx.y * 128;
  int j0 = blockIdx.x * 128;
  int tid = threadIdx.x;
  constexpr int NPASS = 128 * (F / 4) / 256;
  #pragma unroll
  for (int ps = 0; ps < NPASS; ++ps) {
    int e4 = ps * 256 + tid;
    int r = e4 / (F / 4), f4 = (e4 % (F / 4)) * 4;
    *(float4*)&Xi[r*PAD + f4] = *(const float4*)&x[(size_t)(b*2048 + i0 + r)*stride + f4];
    *(float4*)&Xj[r*PAD + f4] = *(const float4*)&x[(size_t)(b*2048 + j0 + r)*stride + f4];
  }
  if (tid < 128) {
    SQI[tid] = sq[b*2048 + i0 + tid];
    SQJ[tid] = sq[b*2048 + j0 + tid];
  }
  __syncthreads();
  int tx = tid & 15, ty = tid >> 4;
  float acc[8][8];
  #pragma unroll
  for (int i = 0; i < 8; ++i)
    #pragma unroll
    for (int j = 0; j < 8; ++j) acc[i][j] = 0.f;
  #pragma unroll 2
  for (int kf = 0; kf < F; kf += 4) {
    float4 av[8], wv[8];
    #pragma unroll
    for (int i = 0; i < 8; ++i) av[i] = *(const float4*)&Xi[(ty + 16*i)*PAD + kf];
    #pragma unroll
    for (int j = 0; j < 8; ++j) wv[j] = *(const float4*)&Xj[(tx + 16*j)*PAD + kf];
    #pragma unroll
    for (int i = 0; i < 8; ++i)
      #pragma unroll
      for (int j = 0; j < 8; ++j) {
        acc[i][j] += av[i].x * wv[j].x;
        acc[i][j] += av[i].y * wv[j].y;
        acc[i][j] += av[i].z * wv[j].z;
        acc[i][j] += av[i].w * wv[j].w;
      }
  }
  #pragma unroll
  for (int i = 0; i < 8; ++i) {
    int row = ty + 16*i;
    float si = SQI[row];
    #pragma unroll
    for (int j = 0; j < 8; ++j) {
      int col = tx + 16*j;
      D[(size_t)(b*512 + blockIdx.y*128 + row)*2048 + j0 + col] =
          si + SQJ[col] - 2.f * acc[i][j];
    }
  }
}

// ---------------- top-30 smallest per row, wave per row ----------------
__global__ __launch_bounds__(256) void k_topk(const float* __restrict__ D, int cbase,
                                              int* __restrict__ knn) {
  int wid  = blockIdx.x * 4 + (threadIdx.x >> 6);  // 0..4095
  int lane = threadIdx.x & 63;
  int b = wid >> 9, il = wid & 511;
  const float* row = D + (size_t)(b*512 + il) * 2048;
  float v[32];
  #pragma unroll
  for (int s = 0; s < 32; ++s) v[s] = row[lane + 64*s];
  const float INFV = __builtin_bit_cast(float, 0x7f800000u);
  int wj = 0;
  #pragma unroll 1
  for (int it = 0; it < 30; ++it) {
    // per-lane scan (strict < keeps earliest slot => lowest j on ties)
    float mv = v[0]; int ms = 0;
    #pragma unroll
    for (int s = 1; s < 32; ++s) {
      bool lt = v[s] < mv;
      mv = lt ? v[s] : mv;
      ms = lt ? s : ms;
    }
    int mj = lane + (ms << 6);
    // cross-lane lexicographic argmin butterfly
    #pragma unroll
    for (int m = 1; m < 64; m <<= 1) {
      float ov = __shfl_xor(mv, m);
      int   oj = __shfl_xor(mj, m);
      bool take = (ov < mv) || ((ov == mv) && (oj < mj));
      mv = take ? ov : mv;
      mj = take ? oj : mj;
    }
    int gj = __builtin_amdgcn_readfirstlane(mj);   // uniform
    if (lane == it) wj = gj;
    int owner = gj & 63, slot = gj >> 6;
    #pragma unroll
    for (int s = 0; s < 32; ++s) {
      if (slot == s) {            // scalar branch
        if (lane == owner) v[s] = INFV;
      }
    }
  }
  if (lane < 30) knn[(size_t)(b*2048 + cbase + il)*30 + lane] = b*2048 + wj;
}

// ---------------- per-point precompute: A0 = xi@(W1a-W1b)+b1, V = x@W1b ----------------
__global__ __launch_bounds__(256) void k_prep(const float* __restrict__ x, int stride, int F,
    const float* __restrict__ W1, const float* __restrict__ b1,
    float* __restrict__ A0, float* __restrict__ V) {
  int p = blockIdx.x * 4 + (threadIdx.x >> 6);
  int lane = threadIdx.x & 63;
  float u = 0.f, v = 0.f;
  for (int f = 0; f < F; ++f) {
    float xv = x[(size_t)p*stride + f];
    float wa = W1[f*64 + lane];
    float wb = W1[(F + f)*64 + lane];
    u += xv * (wa - wb);
    v += xv * wb;
  }
  A0[p*64 + lane] = u + b1[lane];
  V[p*64 + lane]  = v;
}

// ---------------- edge conv: out = max_k relu((A0_i+V_j)*g+be) @ W2 + b2 ----------------
__global__ __launch_bounds__(256) void k_edge(const float* __restrict__ A0,
    const float* __restrict__ V, const int* __restrict__ knn,
    const float* __restrict__ W2, const float* __restrict__ b2,
    const float* __restrict__ g, const float* __restrict__ be,
    float* __restrict__ out, int ostride) {
  int p = blockIdx.x * 4 + (threadIdx.x >> 6);
  int lane = threadIdx.x & 63;         // = output channel c'
  float w2c[64];
  #pragma unroll
  for (int c = 0; c < 64; ++c) w2c[c] = W2[c*64 + lane];
  float arow = A0[p*64 + lane];
  float gg = g[lane], bbe = be[lane];
  const int* kr = knn + p*30;
  float m = -3.0e38f;
  int j = kr[0];
  float vg = V[(size_t)j*64 + lane];
  #pragma unroll 1
  for (int k = 0; k < 30; ++k) {
    int jn = kr[k < 29 ? k + 1 : 29];
    float vgn = V[(size_t)jn*64 + lane];     // prefetch next
    float pre = (arow + vg) * gg + bbe;
    float h1 = pre > 0.f ? pre : 0.f;
    u32 hb = __builtin_bit_cast(u32, h1);
    float s0 = 0.f, s1 = 0.f, s2 = 0.f, s3 = 0.f;
    #pragma unroll
    for (int c = 0; c < 64; c += 4) {
      s0 += __builtin_bit_cast(float, (u32)__builtin_amdgcn_readlane((int)hb, c+0)) * w2c[c+0];
      s1 += __builtin_bit_cast(float, (u32)__builtin_amdgcn_readlane((int)hb, c+1)) * w2c[c+1];
      s2 += __builtin_bit_cast(float, (u32)__builtin_amdgcn_readlane((int)hb, c+2)) * w2c[c+2];
      s3 += __builtin_bit_cast(float, (u32)__builtin_amdgcn_readlane((int)hb, c+3)) * w2c[c+3];
    }
    float h2 = (s0 + s1) + (s2 + s3);
    m = m > h2 ? m : h2;
    vg = vgn;
  }
  out[(size_t)p*ostride + lane] = m + b2[lane];
}

// ---------------- f32 GEMM + bias + optional relu ----------------
template<int BM, int BN, int TM, int TN>
__global__ __launch_bounds__(256) void k_gemm(const float* __restrict__ Ag, int lda,
    const float* __restrict__ Wg, const float* __restrict__ bg,
    float* __restrict__ Cg, int ldc, int N, int K, int dorelu) {
  constexpr int BK = 32;
  constexpr int PS = BK + 4;
  __shared__ __align__(16) float As[BM * PS];
  __shared__ __align__(16) float Ws[BN * PS];
  int tid = threadIdx.x;
  int tx = tid & 15, ty = tid >> 4;
  int m0 = blockIdx.y * BM, n0 = blockIdx.x * BN;
  float acc[TM][TN];
  #pragma unroll
  for (int i = 0; i < TM; ++i)
    #pragma unroll
    for (int j = 0; j < TN; ++j) acc[i][j] = 0.f;
  for (int k0 = 0; k0 < K; k0 += BK) {
    #pragma unroll
    for (int ps = 0; ps < BM*8/256; ++ps) {
      int e4 = ps*256 + tid;
      int r = e4 >> 3, c4 = (e4 & 7) << 2;
      *(float4*)&As[r*PS + c4] = *(const float4*)&Ag[(size_t)(m0 + r)*lda + k0 + c4];
    }
    #pragma unroll
    for (int ps = 0; ps < BK*BN/256; ++ps) {
      int e = ps*256 + tid;
      int kr = e / BN, nc = e % BN;
      Ws[nc*PS + kr] = Wg[(size_t)(k0 + kr)*N + n0 + nc];
    }
    __syncthreads();
    #pragma unroll 2
    for (int kq = 0; kq < BK; kq += 4) {
      float4 av[TM], wv[TN];
      #pragma unroll
      for (int i = 0; i < TM; ++i) av[i] = *(const float4*)&As[(ty + 16*i)*PS + kq];
      #pragma unroll
      for (int j = 0; j < TN; ++j) wv[j] = *(const float4*)&Ws[(tx + 16*j)*PS + kq];
      #pragma unroll
      for (int i = 0; i < TM; ++i)
        #pragma unroll
        for (int j = 0; j < TN; ++j) {
          acc[i][j] += av[i].x * wv[j].x;
          acc[i][j] += av[i].y * wv[j].y;
          acc[i][j] += av[i].z * wv[j].z;
          acc[i][j] += av[i].w * wv[j].w;
        }
    }
    __syncthreads();
  }
  #pragma unroll
  for (int j = 0; j < TN; ++j) {
    float bb = bg[n0 + tx + 16*j];
    #pragma unroll
    for (int i = 0; i < TM; ++i) {
      float vv = acc[i][j] + bb;
      if (dorelu) vv = vv > 0.f ? vv : 0.f;
      Cg[(size_t)(m0 + ty + 16*i)*ldc + n0 + tx + 16*j] = vv;
    }
  }
}

// ---------------- head: 128->13 + log_softmax, lane per point ----------------
__global__ __launch_bounds__(256) void k_head(const float* __restrict__ H3,
    const float* __restrict__ W4, const float* __restrict__ b4,
    float* __restrict__ out0, int pbase) {
  __shared__ float w4s[128 * 13];
  __shared__ float b4s[13];
  for (int e = threadIdx.x; e < 128*13; e += 256) w4s[e] = W4[e];
  if (threadIdx.x < 13) b4s[threadIdx.x] = b4[threadIdx.x];
  __syncthreads();
  int pl = blockIdx.x * 256 + threadIdx.x;
  float acc[13];
  #pragma unroll
  for (int c = 0; c < 13; ++c) acc[c] = b4s[c];
  const float* hr = H3 + (size_t)pl * 128;
  #pragma unroll 1
  for (int k = 0; k < 128; k += 4) {
    float4 h = *(const float4*)&hr[k];
    #pragma unroll
    for (int c = 0; c < 13; ++c) {
      acc[c] += h.x * w4s[(k+0)*13 + c];
      acc[c] += h.y * w4s[(k+1)*13 + c];
      acc[c] += h.z * w4s[(k+2)*13 + c];
      acc[c] += h.w * w4s[(k+3)*13 + c];
    }
  }
  float mx = acc[0];
  #pragma unroll
  for (int c = 1; c < 13; ++c) mx = fmaxf(mx, acc[c]);
  float s = 0.f;
  #pragma unroll
  for (int c = 0; c < 13; ++c) s += expf(acc[c] - mx);
  float lg = logf(s);
  size_t ob = (size_t)(pbase + pl) * 13;
  #pragma unroll
  for (int c = 0; c < 13; ++c) out0[ob + c] = acc[c] - mx - lg;
}

// ---------------- out1 = x3 ----------------
__global__ void k_out1(const float* __restrict__ hcat, float* __restrict__ out1) {
  int e = blockIdx.x * 256 + threadIdx.x;
  int p = e >> 6, c = e & 63;
  out1[e] = hcat[(size_t)p*192 + 128 + c];
}

extern "C" void kernel_launch(void* const* d_in, const int* in_sizes, int n_in,
                              void* d_out, int out_size, void* d_ws, size_t ws_size,
                              hipStream_t stream) {
  (void)in_sizes; (void)n_in; (void)out_size; (void)ws_size;
  const float* x   = (const float*)d_in[0];
  const float* pos = (const float*)d_in[1];
  const float* cw[3][6];   // W1,b1,g,be,W2,b2 per conv
  for (int c = 0; c < 3; ++c)
    for (int t = 0; t < 6; ++t)
      cw[c][t] = (const float*)d_in[3 + c*6 + t];
  const float *mW[4], *mb[4];
  for (int j = 0; j < 4; ++j) {
    mW[j] = (const float*)d_in[21 + 2*j];
    mb[j] = (const float*)d_in[22 + 2*j];
  }

  float* ws   = (float*)d_ws;
  float* x0   = ws;                        // 131072
  float* sq   = x0 + 131072;               // 16384
  int*   knn  = (int*)(sq + 16384);        // 491520 ints
  float* A0   = (float*)(knn + 491520);    // 1048576
  float* V    = A0 + 1048576;              // 1048576
  float* hcat = V + 1048576;               // 3145728 (x1|x2|x3, stride 192)
  float* U    = hcat + 3145728;            // 8388608 (D chunks, then H1 chunk)
  float* H2c  = U + 8388608;               // 2097152
  float* H3c  = H2c + 2097152;             // 1048576

  float* out0 = (float*)d_out;
  float* out1 = out0 + 8*2048*13;

  k_build_x0<<<64, 256, 0, stream>>>(x, pos, x0);

  for (int c = 0; c < 3; ++c) {
    const float* xin; int stride, F, Fsq;
    if (c == 0)      { xin = x0;        stride = 8;   F = 6;  Fsq = 8;  }
    else if (c == 1) { xin = hcat;      stride = 192; F = 64; Fsq = 64; }
    else             { xin = hcat + 64; stride = 192; F = 64; Fsq = 64; }
    k_sqnorm<<<4096, 256, 0, stream>>>(xin, stride, Fsq, sq);
    for (int ch = 0; ch < 4; ++ch) {
      if (c == 0) k_dist<8> <<<dim3(16,4,8), 256, 0, stream>>>(xin, stride, sq, ch*512, U);
      else        k_dist<64><<<dim3(16,4,8), 256, 0, stream>>>(xin, stride, sq, ch*512, U);
      k_topk<<<1024, 256, 0, stream>>>(U, ch*512, knn);
    }
    k_prep<<<4096, 256, 0, stream>>>(xin, stride, F, cw[c][0], cw[c][1], A0, V);
    k_edge<<<4096, 256, 0, stream>>>(A0, V, knn, cw[c][4], cw[c][5], cw[c][2], cw[c][3],
                                     hcat + 64*c, 192);
  }

  for (int ch = 0; ch < 2; ++ch) {
    const float* Ain = hcat + (size_t)ch * 8192 * 192;
    k_gemm<128,128,8,8><<<dim3(8,64), 256, 0, stream>>>(Ain, 192,  mW[0], mb[0], U,   1024, 1024, 192,  1);
    k_gemm<128, 64,8,4><<<dim3(4,64), 256, 0, stream>>>(U,   1024, mW[1], mb[1], H2c, 256,  256,  1024, 1);
    k_gemm<128, 64,8,4><<<dim3(2,64), 256, 0, stream>>>(H2c, 256,  mW[2], mb[2], H3c, 128,  128,  256,  1);
    k_head<<<32, 256, 0, stream>>>(H3c, mW[3], mb[3], out0, ch*8192);
  }
  k_out1<<<4096, 256, 0, stream>>>(hcat, out1);
}

// Round 3
// 1588.161 us; speedup vs baseline: 1.1263x; 1.1263x over previous
//
#include <hip/hip_runtime.h>

using u32 = unsigned int;
typedef short s8v __attribute__((ext_vector_type(8)));
typedef short s4v __attribute__((ext_vector_type(4)));
typedef float f4v __attribute__((ext_vector_type(4)));

#define DEV static __device__ __forceinline__

// split f32 into hi+lo bf16 (round-to-nearest-even)
DEV void cvt_split(float f, unsigned short& h, unsigned short& l) {
  u32 x = __builtin_bit_cast(u32, f);
  u32 rh = (x + 0x7FFFu + ((x >> 16) & 1u)) & 0xFFFF0000u;
  h = (unsigned short)(rh >> 16);
  float fl = f - __builtin_bit_cast(float, rh);
  u32 y = __builtin_bit_cast(u32, fl);
  l = (unsigned short)((y + 0x7FFFu + ((y >> 16) & 1u)) >> 16);
}

// ---------------- build x0 = [pos, x], padded to 8 cols ----------------
__global__ void k_build_x0(const float* __restrict__ x, const float* __restrict__ pos,
                           float* __restrict__ x0) {
  int p = blockIdx.x * 256 + threadIdx.x;   // 16384 points
  float* o = x0 + (size_t)p * 8;
  o[0] = pos[p*3+0]; o[1] = pos[p*3+1]; o[2] = pos[p*3+2];
  o[3] = x[p*3+0];   o[4] = x[p*3+1];   o[5] = x[p*3+2];
  o[6] = 0.f; o[7] = 0.f;
}

// ---------------- squared norms, wave per point ----------------
__global__ void k_sqnorm(const float* __restrict__ x, int stride, int F,
                         float* __restrict__ sq) {
  int wid  = (blockIdx.x * 256 + threadIdx.x) >> 6;
  int lane = threadIdx.x & 63;
  float v = (lane < F) ? x[(size_t)wid * stride + lane] : 0.f;
  float s = v * v;
  #pragma unroll
  for (int m = 32; m; m >>= 1) s += __shfl_xor(s, m);
  if (lane == 0) sq[wid] = s;
}

// ---------------- distance GEMM: D = sq_i + sq_j - 2 * Xi . Xj ----------------
template<int F>
__global__ __launch_bounds__(256) void k_dist(const float* __restrict__ x, int stride,
    const float* __restrict__ sq, int cbase, float* __restrict__ D) {
  constexpr int PAD = F + 4;
  __shared__ __align__(16) float Xi[128 * PAD];
  __shared__ __align__(16) float Xj[128 * PAD];
  __shared__ float SQI[128], SQJ[128];
  int b  = blockIdx.z;
  int i0 = cbase + blockIdx.y * 128;
  int j0 = blockIdx.x * 128;
  int tid = threadIdx.x;
  constexpr int NPASS = 128 * (F / 4) / 256;
  #pragma unroll
  for (int ps = 0; ps < NPASS; ++ps) {
    int e4 = ps * 256 + tid;
    int r = e4 / (F / 4), f4 = (e4 % (F / 4)) * 4;
    *(float4*)&Xi[r*PAD + f4] = *(const float4*)&x[(size_t)(b*2048 + i0 + r)*stride + f4];
    *(float4*)&Xj[r*PAD + f4] = *(const float4*)&x[(size_t)(b*2048 + j0 + r)*stride + f4];
  }
  if (tid < 128) {
    SQI[tid] = sq[b*2048 + i0 + tid];
    SQJ[tid] = sq[b*2048 + j0 + tid];
  }
  __syncthreads();
  int tx = tid & 15, ty = tid >> 4;
  float acc[8][8];
  #pragma unroll
  for (int i = 0; i < 8; ++i)
    #pragma unroll
    for (int j = 0; j < 8; ++j) acc[i][j] = 0.f;
  #pragma unroll 2
  for (int kf = 0; kf < F; kf += 4) {
    float4 av[8], wv[8];
    #pragma unroll
    for (int i = 0; i < 8; ++i) av[i] = *(const float4*)&Xi[(ty + 16*i)*PAD + kf];
    #pragma unroll
    for (int j = 0; j < 8; ++j) wv[j] = *(const float4*)&Xj[(tx + 16*j)*PAD + kf];
    #pragma unroll
    for (int i = 0; i < 8; ++i)
      #pragma unroll
      for (int j = 0; j < 8; ++j) {
        acc[i][j] += av[i].x * wv[j].x;
        acc[i][j] += av[i].y * wv[j].y;
        acc[i][j] += av[i].z * wv[j].z;
        acc[i][j] += av[i].w * wv[j].w;
      }
  }
  #pragma unroll
  for (int i = 0; i < 8; ++i) {
    int row = ty + 16*i;
    float si = SQI[row];
    #pragma unroll
    for (int j = 0; j < 8; ++j) {
      int col = tx + 16*j;
      D[(size_t)(b*512 + blockIdx.y*128 + row)*2048 + j0 + col] =
          si + SQJ[col] - 2.f * acc[i][j];
    }
  }
}

// ---------------- top-30 smallest per row, wave per row ----------------
__global__ __launch_bounds__(256) void k_topk(const float* __restrict__ D, int cbase,
                                              int* __restrict__ knn) {
  int wid  = blockIdx.x * 4 + (threadIdx.x >> 6);  // 0..4095
  int lane = threadIdx.x & 63;
  int b = wid >> 9, il = wid & 511;
  const float* row = D + (size_t)(b*512 + il) * 2048;
  float v[32];
  #pragma unroll
  for (int s = 0; s < 32; ++s) v[s] = row[lane + 64*s];
  const float INFV = __builtin_bit_cast(float, 0x7f800000u);
  int wj = 0;
  #pragma unroll 1
  for (int it = 0; it < 30; ++it) {
    float mv = v[0]; int ms = 0;
    #pragma unroll
    for (int s = 1; s < 32; ++s) {
      bool lt = v[s] < mv;
      mv = lt ? v[s] : mv;
      ms = lt ? s : ms;
    }
    int mj = lane + (ms << 6);
    #pragma unroll
    for (int m = 1; m < 64; m <<= 1) {
      float ov = __shfl_xor(mv, m);
      int   oj = __shfl_xor(mj, m);
      bool take = (ov < mv) || ((ov == mv) && (oj < mj));
      mv = take ? ov : mv;
      mj = take ? oj : mj;
    }
    int gj = __builtin_amdgcn_readfirstlane(mj);
    if (lane == it) wj = gj;
    int owner = gj & 63, slot = gj >> 6;
    #pragma unroll
    for (int s = 0; s < 32; ++s) {
      if (slot == s) {
        if (lane == owner) v[s] = INFV;
      }
    }
  }
  if (lane < 30) knn[(size_t)(b*2048 + cbase + il)*30 + lane] = b*2048 + wj;
}

// ---------------- per-point precompute: A0 = xi@(W1a-W1b)+b1, V = x@W1b ----------------
__global__ __launch_bounds__(256) void k_prep(const float* __restrict__ x, int stride, int F,
    const float* __restrict__ W1, const float* __restrict__ b1,
    float* __restrict__ A0, float* __restrict__ V) {
  int p = blockIdx.x * 4 + (threadIdx.x >> 6);
  int lane = threadIdx.x & 63;
  float u = 0.f, v = 0.f;
  for (int f = 0; f < F; ++f) {
    float xv = x[(size_t)p*stride + f];
    float wa = W1[f*64 + lane];
    float wb = W1[(F + f)*64 + lane];
    u += xv * (wa - wb);
    v += xv * wb;
  }
  A0[p*64 + lane] = u + b1[lane];
  V[p*64 + lane]  = v;
}

// ---------------- edge conv: out = max_k relu((A0_i+V_j)*g+be) @ W2 + b2 ----------------
__global__ __launch_bounds__(256) void k_edge(const float* __restrict__ A0,
    const float* __restrict__ V, const int* __restrict__ knn,
    const float* __restrict__ W2, const float* __restrict__ b2,
    const float* __restrict__ g, const float* __restrict__ be,
    float* __restrict__ out, int ostride) {
  int p = blockIdx.x * 4 + (threadIdx.x >> 6);
  int lane = threadIdx.x & 63;         // = output channel c'
  float w2c[64];
  #pragma unroll
  for (int c = 0; c < 64; ++c) w2c[c] = W2[c*64 + lane];
  float arow = A0[p*64 + lane];
  float gg = g[lane], bbe = be[lane];
  const int* kr = knn + p*30;
  float m = -3.0e38f;
  int j = kr[0];
  float vg = V[(size_t)j*64 + lane];
  #pragma unroll 1
  for (int k = 0; k < 30; ++k) {
    int jn = kr[k < 29 ? k + 1 : 29];
    float vgn = V[(size_t)jn*64 + lane];     // prefetch next
    float pre = (arow + vg) * gg + bbe;
    float h1 = pre > 0.f ? pre : 0.f;
    u32 hb = __builtin_bit_cast(u32, h1);
    float s0 = 0.f, s1 = 0.f, s2 = 0.f, s3 = 0.f;
    #pragma unroll
    for (int c = 0; c < 64; c += 4) {
      s0 += __builtin_bit_cast(float, (u32)__builtin_amdgcn_readlane((int)hb, c+0)) * w2c[c+0];
      s1 += __builtin_bit_cast(float, (u32)__builtin_amdgcn_readlane((int)hb, c+1)) * w2c[c+1];
      s2 += __builtin_bit_cast(float, (u32)__builtin_amdgcn_readlane((int)hb, c+2)) * w2c[c+2];
      s3 += __builtin_bit_cast(float, (u32)__builtin_amdgcn_readlane((int)hb, c+3)) * w2c[c+3];
    }
    float h2 = (s0 + s1) + (s2 + s3);
    m = m > h2 ? m : h2;
    vg = vgn;
  }
  out[(size_t)p*ostride + lane] = m + b2[lane];
}

// ---------------- split-bf16 MFMA GEMM: C = relu(A@W + b) ----------------
// BM=128, BN=128, BK=32; 4 waves, each 64x64; 3 MFMA products (hi*hi, hi*lo, lo*hi)
__global__ __launch_bounds__(256) void k_mlp(const float* __restrict__ Ag, int lda,
    const float* __restrict__ Wg, const float* __restrict__ bg,
    float* __restrict__ Cg, int ldc, int N, int K, int dorelu) {
  constexpr int PK = 40;   // padded BK in shorts (80 B rows: 2-way max per quarter-wave)
  __shared__ __align__(16) unsigned short Ah[128*PK];
  __shared__ __align__(16) unsigned short Al[128*PK];
  __shared__ __align__(16) unsigned short Wh[128*PK];
  __shared__ __align__(16) unsigned short Wl[128*PK];
  int tid  = threadIdx.x;
  int wave = tid >> 6, lane = tid & 63;
  int wm = (wave >> 1) * 64, wn = (wave & 1) * 64;
  int lr = lane & 15, kb = lane >> 4;          // fragment row/col, k-block (0..3)
  int m0 = blockIdx.y * 128, n0 = blockIdx.x * 128;

  f4v acc[4][4];
  #pragma unroll
  for (int i = 0; i < 4; ++i)
    #pragma unroll
    for (int j = 0; j < 4; ++j) acc[i][j] = (f4v)(0.f);

  for (int k0 = 0; k0 < K; k0 += 32) {
    // stage A tile: 128 rows x 32 k (f32) -> split bf16 hi/lo, [m][k] layout
    #pragma unroll
    for (int p = 0; p < 4; ++p) {
      int e4 = p * 256 + tid;                  // 0..1023 float4s
      int r = e4 >> 3, c4 = (e4 & 7) << 2;
      float4 a = *(const float4*)&Ag[(size_t)(m0 + r)*lda + k0 + c4];
      unsigned short h0,h1,h2,h3,l0,l1,l2,l3;
      cvt_split(a.x, h0, l0); cvt_split(a.y, h1, l1);
      cvt_split(a.z, h2, l2); cvt_split(a.w, h3, l3);
      *(s4v*)&Ah[r*PK + c4] = s4v{(short)h0,(short)h1,(short)h2,(short)h3};
      *(s4v*)&Al[r*PK + c4] = s4v{(short)l0,(short)l1,(short)l2,(short)l3};
    }
    // stage W tile: 32 k-rows x 128 n (f32), transposed into [n][k] layout
    #pragma unroll
    for (int p = 0; p < 4; ++p) {
      int e4 = p * 256 + tid;
      int kr = e4 >> 5, nc4 = (e4 & 31) << 2;
      float4 w = *(const float4*)&Wg[(size_t)(k0 + kr)*N + n0 + nc4];
      unsigned short h, l;
      cvt_split(w.x, h, l); Wh[(nc4+0)*PK + kr] = h; Wl[(nc4+0)*PK + kr] = l;
      cvt_split(w.y, h, l); Wh[(nc4+1)*PK + kr] = h; Wl[(nc4+1)*PK + kr] = l;
      cvt_split(w.z, h, l); Wh[(nc4+2)*PK + kr] = h; Wl[(nc4+2)*PK + kr] = l;
      cvt_split(w.w, h, l); Wh[(nc4+3)*PK + kr] = h; Wl[(nc4+3)*PK + kr] = l;
    }
    __syncthreads();

    s8v bh[4], bl[4];
    #pragma unroll
    for (int jf = 0; jf < 4; ++jf) {
      int n = wn + jf*16 + lr;
      bh[jf] = *(const s8v*)&Wh[n*PK + kb*8];
      bl[jf] = *(const s8v*)&Wl[n*PK + kb*8];
    }
    #pragma unroll
    for (int mf = 0; mf < 4; ++mf) {
      int m = wm + mf*16 + lr;
      s8v ah = *(const s8v*)&Ah[m*PK + kb*8];
      s8v al = *(const s8v*)&Al[m*PK + kb*8];
      #pragma unroll
      for (int jf = 0; jf < 4; ++jf) {
        acc[mf][jf] = __builtin_amdgcn_mfma_f32_16x16x32_bf16(ah, bh[jf], acc[mf][jf], 0, 0, 0);
        acc[mf][jf] = __builtin_amdgcn_mfma_f32_16x16x32_bf16(ah, bl[jf], acc[mf][jf], 0, 0, 0);
        acc[mf][jf] = __builtin_amdgcn_mfma_f32_16x16x32_bf16(al, bh[jf], acc[mf][jf], 0, 0, 0);
      }
    }
    __syncthreads();
  }

  // epilogue: D row=(lane>>4)*4+reg, col=lane&15
  #pragma unroll
  for (int jf = 0; jf < 4; ++jf) {
    int n = n0 + wn + jf*16 + lr;
    float bb = bg[n];
    #pragma unroll
    for (int mf = 0; mf < 4; ++mf) {
      #pragma unroll
      for (int r = 0; r < 4; ++r) {
        int m = m0 + wm + mf*16 + kb*4 + r;
        float v = acc[mf][jf][r] + bb;
        if (dorelu) v = v > 0.f ? v : 0.f;
        Cg[(size_t)m*ldc + n] = v;
      }
    }
  }
}

// ---------------- head: 128->13 + log_softmax, lane per point ----------------
__global__ __launch_bounds__(256) void k_head(const float* __restrict__ H3,
    const float* __restrict__ W4, const float* __restrict__ b4,
    float* __restrict__ out0, int pbase) {
  __shared__ float w4s[128 * 13];
  __shared__ float b4s[13];
  for (int e = threadIdx.x; e < 128*13; e += 256) w4s[e] = W4[e];
  if (threadIdx.x < 13) b4s[threadIdx.x] = b4[threadIdx.x];
  __syncthreads();
  int pl = blockIdx.x * 256 + threadIdx.x;
  float acc[13];
  #pragma unroll
  for (int c = 0; c < 13; ++c) acc[c] = b4s[c];
  const float* hr = H3 + (size_t)pl * 128;
  #pragma unroll 1
  for (int k = 0; k < 128; k += 4) {
    float4 h = *(const float4*)&hr[k];
    #pragma unroll
    for (int c = 0; c < 13; ++c) {
      acc[c] += h.x * w4s[(k+0)*13 + c];
      acc[c] += h.y * w4s[(k+1)*13 + c];
      acc[c] += h.z * w4s[(k+2)*13 + c];
      acc[c] += h.w * w4s[(k+3)*13 + c];
    }
  }
  float mx = acc[0];
  #pragma unroll
  for (int c = 1; c < 13; ++c) mx = fmaxf(mx, acc[c]);
  float s = 0.f;
  #pragma unroll
  for (int c = 0; c < 13; ++c) s += expf(acc[c] - mx);
  float lg = logf(s);
  size_t ob = (size_t)(pbase + pl) * 13;
  #pragma unroll
  for (int c = 0; c < 13; ++c) out0[ob + c] = acc[c] - mx - lg;
}

// ---------------- out1 = x3 ----------------
__global__ void k_out1(const float* __restrict__ hcat, float* __restrict__ out1) {
  int e = blockIdx.x * 256 + threadIdx.x;
  int p = e >> 6, c = e & 63;
  out1[e] = hcat[(size_t)p*192 + 128 + c];
}

extern "C" void kernel_launch(void* const* d_in, const int* in_sizes, int n_in,
                              void* d_out, int out_size, void* d_ws, size_t ws_size,
                              hipStream_t stream) {
  (void)in_sizes; (void)n_in; (void)out_size; (void)ws_size;
  const float* x   = (const float*)d_in[0];
  const float* pos = (const float*)d_in[1];
  const float* cw[3][6];   // W1,b1,g,be,W2,b2 per conv
  for (int c = 0; c < 3; ++c)
    for (int t = 0; t < 6; ++t)
      cw[c][t] = (const float*)d_in[3 + c*6 + t];
  const float *mW[4], *mb[4];
  for (int j = 0; j < 4; ++j) {
    mW[j] = (const float*)d_in[21 + 2*j];
    mb[j] = (const float*)d_in[22 + 2*j];
  }

  float* ws   = (float*)d_ws;
  float* x0   = ws;                        // 131072
  float* sq   = x0 + 131072;               // 16384
  int*   knn  = (int*)(sq + 16384);        // 491520 ints
  float* A0   = (float*)(knn + 491520);    // 1048576
  float* V    = A0 + 1048576;              // 1048576
  float* hcat = V + 1048576;               // 3145728 (x1|x2|x3, stride 192)
  float* U    = hcat + 3145728;            // 8388608 (D chunks, then H1 chunk)
  float* H2c  = U + 8388608;               // 2097152
  float* H3c  = H2c + 2097152;             // 1048576

  float* out0 = (float*)d_out;
  float* out1 = out0 + 8*2048*13;

  k_build_x0<<<64, 256, 0, stream>>>(x, pos, x0);

  for (int c = 0; c < 3; ++c) {
    const float* xin; int stride, F, Fsq;
    if (c == 0)      { xin = x0;        stride = 8;   F = 6;  Fsq = 8;  }
    else if (c == 1) { xin = hcat;      stride = 192; F = 64; Fsq = 64; }
    else             { xin = hcat + 64; stride = 192; F = 64; Fsq = 64; }
    k_sqnorm<<<4096, 256, 0, stream>>>(xin, stride, Fsq, sq);
    for (int ch = 0; ch < 4; ++ch) {
      if (c == 0) k_dist<8> <<<dim3(16,4,8), 256, 0, stream>>>(xin, stride, sq, ch*512, U);
      else        k_dist<64><<<dim3(16,4,8), 256, 0, stream>>>(xin, stride, sq, ch*512, U);
      k_topk<<<1024, 256, 0, stream>>>(U, ch*512, knn);
    }
    k_prep<<<4096, 256, 0, stream>>>(xin, stride, F, cw[c][0], cw[c][1], A0, V);
    k_edge<<<4096, 256, 0, stream>>>(A0, V, knn, cw[c][4], cw[c][5], cw[c][2], cw[c][3],
                                     hcat + 64*c, 192);
  }

  for (int ch = 0; ch < 2; ++ch) {
    const float* Ain = hcat + (size_t)ch * 8192 * 192;
    k_mlp<<<dim3(8,64), 256, 0, stream>>>(Ain, 192,  mW[0], mb[0], U,   1024, 1024, 192,  1);
    k_mlp<<<dim3(2,64), 256, 0, stream>>>(U,   1024, mW[1], mb[1], H2c, 256,  256,  1024, 1);
    k_mlp<<<dim3(1,64), 256, 0, stream>>>(H2c, 256,  mW[2], mb[2], H3c, 128,  128,  256,  1);
    k_head<<<32, 256, 0, stream>>>(H3c, mW[3], mb[3], out0, ch*8192);
  }
  k_out1<<<4096, 256, 0, stream>>>(hcat, out1);
}

// Round 5
// 1342.914 us; speedup vs baseline: 1.3320x; 1.1826x over previous
//
#include <hip/hip_runtime.h>

using u16 = unsigned short;
using u32 = unsigned int;
typedef short s8v __attribute__((ext_vector_type(8)));
typedef short s4v __attribute__((ext_vector_type(4)));
typedef float f4v __attribute__((ext_vector_type(4)));

#define DEV static __device__ __forceinline__

// split f32 into hi+lo bf16 (round-to-nearest-even)
DEV void cvt_split(float f, u16& h, u16& l) {
  u32 x = __builtin_bit_cast(u32, f);
  u32 rh = (x + 0x7FFFu + ((x >> 16) & 1u)) & 0xFFFF0000u;
  h = (u16)(rh >> 16);
  float fl = f - __builtin_bit_cast(float, rh);
  u32 y = __builtin_bit_cast(u32, fl);
  l = (u16)((y + 0x7FFFu + ((y >> 16) & 1u)) >> 16);
}

// ---------------- split + transpose weights: W[K][N] f32 -> Wh/Wl [N][PK] bf16 ----------------
__global__ void k_splitw(const float* __restrict__ W, int K, int N, int PK,
                         u16* __restrict__ Wh, u16* __restrict__ Wl) {
  int e = blockIdx.x * 256 + threadIdx.x;
  if (e >= K * N) return;
  int k = e / N, n = e % N;
  u16 h, l;
  cvt_split(W[e], h, l);
  Wh[(size_t)n * PK + k] = h;
  Wl[(size_t)n * PK + k] = l;
}

// ---------------- build x0 = [pos, x], padded to 8 cols ----------------
__global__ void k_build_x0(const float* __restrict__ x, const float* __restrict__ pos,
                           float* __restrict__ x0) {
  int p = blockIdx.x * 256 + threadIdx.x;
  float* o = x0 + (size_t)p * 8;
  o[0] = pos[p*3+0]; o[1] = pos[p*3+1]; o[2] = pos[p*3+2];
  o[3] = x[p*3+0];   o[4] = x[p*3+1];   o[5] = x[p*3+2];
  o[6] = 0.f; o[7] = 0.f;
}

// ---------------- squared norms, wave per point ----------------
__global__ void k_sqnorm(const float* __restrict__ x, int stride, int F,
                         float* __restrict__ sq) {
  int wid  = (blockIdx.x * 256 + threadIdx.x) >> 6;
  int lane = threadIdx.x & 63;
  float v = (lane < F) ? x[(size_t)wid * stride + lane] : 0.f;
  float s = v * v;
  #pragma unroll
  for (int m = 32; m; m >>= 1) s += __shfl_xor(s, m);
  if (lane == 0) sq[wid] = s;
}

// ---------------- distance GEMM: D = sq_i + sq_j - 2 * Xi . Xj ----------------
template<int F>
__global__ __launch_bounds__(256) void k_dist(const float* __restrict__ x, int stride,
    const float* __restrict__ sq, int cbase, float* __restrict__ D) {
  constexpr int PAD = F + 4;
  __shared__ __align__(16) float Xi[128 * PAD];
  __shared__ __align__(16) float Xj[128 * PAD];
  __shared__ float SQI[128], SQJ[128];
  int b  = blockIdx.z;
  int i0 = cbase + blockIdx.y * 128;
  int j0 = blockIdx.x * 128;
  int tid = threadIdx.x;
  constexpr int NPASS = 128 * (F / 4) / 256;
  #pragma unroll
  for (int ps = 0; ps < NPASS; ++ps) {
    int e4 = ps * 256 + tid;
    int r = e4 / (F / 4), f4 = (e4 % (F / 4)) * 4;
    *(float4*)&Xi[r*PAD + f4] = *(const float4*)&x[(size_t)(b*2048 + i0 + r)*stride + f4];
    *(float4*)&Xj[r*PAD + f4] = *(const float4*)&x[(size_t)(b*2048 + j0 + r)*stride + f4];
  }
  if (tid < 128) {
    SQI[tid] = sq[b*2048 + i0 + tid];
    SQJ[tid] = sq[b*2048 + j0 + tid];
  }
  __syncthreads();
  int tx = tid & 15, ty = tid >> 4;
  float acc[8][8];
  #pragma unroll
  for (int i = 0; i < 8; ++i)
    #pragma unroll
    for (int j = 0; j < 8; ++j) acc[i][j] = 0.f;
  #pragma unroll 2
  for (int kf = 0; kf < F; kf += 4) {
    float4 av[8], wv[8];
    #pragma unroll
    for (int i = 0; i < 8; ++i) av[i] = *(const float4*)&Xi[(ty + 16*i)*PAD + kf];
    #pragma unroll
    for (int j = 0; j < 8; ++j) wv[j] = *(const float4*)&Xj[(tx + 16*j)*PAD + kf];
    #pragma unroll
    for (int i = 0; i < 8; ++i)
      #pragma unroll
      for (int j = 0; j < 8; ++j) {
        acc[i][j] += av[i].x * wv[j].x;
        acc[i][j] += av[i].y * wv[j].y;
        acc[i][j] += av[i].z * wv[j].z;
        acc[i][j] += av[i].w * wv[j].w;
      }
  }
  #pragma unroll
  for (int i = 0; i < 8; ++i) {
    int row = ty + 16*i;
    float si = SQI[row];
    #pragma unroll
    for (int j = 0; j < 8; ++j) {
      int col = tx + 16*j;
      D[(size_t)(b*512 + blockIdx.y*128 + row)*2048 + j0 + col] =
          si + SQJ[col] - 2.f * acc[i][j];
    }
  }
}

// ---------------- top-30 smallest per row, wave per row ----------------
__global__ __launch_bounds__(256) void k_topk(const float* __restrict__ D, int cbase,
                                              int* __restrict__ knn) {
  int wid  = blockIdx.x * 4 + (threadIdx.x >> 6);
  int lane = threadIdx.x & 63;
  int b = wid >> 9, il = wid & 511;
  const float* row = D + (size_t)(b*512 + il) * 2048;
  float v[32];
  #pragma unroll
  for (int s = 0; s < 32; ++s) v[s] = row[lane + 64*s];
  const float INFV = __builtin_bit_cast(float, 0x7f800000u);
  int wj = 0;
  #pragma unroll 1
  for (int it = 0; it < 30; ++it) {
    float mv = v[0]; int ms = 0;
    #pragma unroll
    for (int s = 1; s < 32; ++s) {
      bool lt = v[s] < mv;
      mv = lt ? v[s] : mv;
      ms = lt ? s : ms;
    }
    int mj = lane + (ms << 6);
    #pragma unroll
    for (int m = 1; m < 64; m <<= 1) {
      float ov = __shfl_xor(mv, m);
      int   oj = __shfl_xor(mj, m);
      bool take = (ov < mv) || ((ov == mv) && (oj < mj));
      mv = take ? ov : mv;
      mj = take ? oj : mj;
    }
    int gj = __builtin_amdgcn_readfirstlane(mj);
    if (lane == it) wj = gj;
    int owner = gj & 63, slot = gj >> 6;
    #pragma unroll
    for (int s = 0; s < 32; ++s) {
      if (slot == s) {
        if (lane == owner) v[s] = INFV;
      }
    }
  }
  if (lane < 30) knn[(size_t)(b*2048 + cbase + il)*30 + lane] = b*2048 + wj;
}

// ---------------- per-point precompute: A0 = xi@(W1a-W1b)+b1, V = x@W1b ----------------
__global__ __launch_bounds__(256) void k_prep(const float* __restrict__ x, int stride, int F,
    const float* __restrict__ W1, const float* __restrict__ b1,
    float* __restrict__ A0, float* __restrict__ V) {
  int p = blockIdx.x * 4 + (threadIdx.x >> 6);
  int lane = threadIdx.x & 63;
  float u = 0.f, v = 0.f;
  for (int f = 0; f < F; ++f) {
    float xv = x[(size_t)p*stride + f];
    float wa = W1[f*64 + lane];
    float wb = W1[(F + f)*64 + lane];
    u += xv * (wa - wb);
    v += xv * wb;
  }
  A0[p*64 + lane] = u + b1[lane];
  V[p*64 + lane]  = v;
}

// ---------------- edge conv, f32 VALU (exact path; used when output feeds a later KNN) ----------------
__global__ __launch_bounds__(256) void k_edge_v(const float* __restrict__ A0,
    const float* __restrict__ V, const int* __restrict__ knn,
    const float* __restrict__ W2, const float* __restrict__ b2,
    const float* __restrict__ g, const float* __restrict__ be,
    float* __restrict__ out, int ostride) {
  int p = blockIdx.x * 4 + (threadIdx.x >> 6);
  int lane = threadIdx.x & 63;         // = output channel c'
  float w2c[64];
  #pragma unroll
  for (int c = 0; c < 64; ++c) w2c[c] = W2[c*64 + lane];
  float arow = A0[p*64 + lane];
  float gg = g[lane], bbe = be[lane];
  const int* kr = knn + p*30;
  float m = -3.0e38f;
  int j = kr[0];
  float vg = V[(size_t)j*64 + lane];
  #pragma unroll 1
  for (int k = 0; k < 30; ++k) {
    int jn = kr[k < 29 ? k + 1 : 29];
    float vgn = V[(size_t)jn*64 + lane];     // prefetch next
    float pre = (arow + vg) * gg + bbe;
    float h1 = pre > 0.f ? pre : 0.f;
    u32 hb = __builtin_bit_cast(u32, h1);
    float s0 = 0.f, s1 = 0.f, s2 = 0.f, s3 = 0.f;
    #pragma unroll
    for (int c = 0; c < 64; c += 4) {
      s0 += __builtin_bit_cast(float, (u32)__builtin_amdgcn_readlane((int)hb, c+0)) * w2c[c+0];
      s1 += __builtin_bit_cast(float, (u32)__builtin_amdgcn_readlane((int)hb, c+1)) * w2c[c+1];
      s2 += __builtin_bit_cast(float, (u32)__builtin_amdgcn_readlane((int)hb, c+2)) * w2c[c+2];
      s3 += __builtin_bit_cast(float, (u32)__builtin_amdgcn_readlane((int)hb, c+3)) * w2c[c+3];
    }
    float h2 = (s0 + s1) + (s2 + s3);
    m = m > h2 ? m : h2;
    vg = vgn;
  }
  out[(size_t)p*ostride + lane] = m + b2[lane];
}

// ---------------- edge conv via MFMA (3-pass split-bf16; ONLY for conv3: no downstream KNN) ----------------
__global__ __launch_bounds__(256) void k_edge_m(const float* __restrict__ A0,
    const float* __restrict__ V, const int* __restrict__ knn,
    const u16* __restrict__ W2h, const u16* __restrict__ W2l,
    const float* __restrict__ b2,
    const float* __restrict__ g, const float* __restrict__ be,
    float* __restrict__ out, int ostride) {
  constexpr int PKW = 72;
  int p = blockIdx.x * 4 + (threadIdx.x >> 6);
  int lane = threadIdx.x & 63;
  int lr = lane & 15, kb = lane >> 4;

  const int* kr = knn + (size_t)p * 30;
  int j0 = kr[lr];
  int j1 = kr[lr + 16 < 30 ? lr + 16 : 29];

  // B fragments (W2 tiny & L2-hot): [jf][ks]
  s8v bh[4][2], bl[4][2];
  #pragma unroll
  for (int jf = 0; jf < 4; ++jf) {
    int n = jf*16 + lr;
    #pragma unroll
    for (int ks = 0; ks < 2; ++ks) {
      bh[jf][ks] = *(const s8v*)&W2h[n*PKW + ks*32 + kb*8];
      bl[jf][ks] = *(const s8v*)&W2l[n*PKW + ks*32 + kb*8];
    }
  }

  // base = A0*g + be, gs = g  for this lane's 16 channels: [ks][e]
  float base[2][8], gs[2][8];
  #pragma unroll
  for (int ks = 0; ks < 2; ++ks) {
    int cb = ks*32 + kb*8;
    float4 a0 = *(const float4*)&A0[(size_t)p*64 + cb];
    float4 a1 = *(const float4*)&A0[(size_t)p*64 + cb + 4];
    float4 g0 = *(const float4*)&g[cb];
    float4 g1 = *(const float4*)&g[cb + 4];
    float4 e0 = *(const float4*)&be[cb];
    float4 e1 = *(const float4*)&be[cb + 4];
    base[ks][0]=a0.x*g0.x+e0.x; base[ks][1]=a0.y*g0.y+e0.y;
    base[ks][2]=a0.z*g0.z+e0.z; base[ks][3]=a0.w*g0.w+e0.w;
    base[ks][4]=a1.x*g1.x+e1.x; base[ks][5]=a1.y*g1.y+e1.y;
    base[ks][6]=a1.z*g1.z+e1.z; base[ks][7]=a1.w*g1.w+e1.w;
    gs[ks][0]=g0.x; gs[ks][1]=g0.y; gs[ks][2]=g0.z; gs[ks][3]=g0.w;
    gs[ks][4]=g1.x; gs[ks][5]=g1.y; gs[ks][6]=g1.z; gs[ks][7]=g1.w;
  }

  // A fragments: h1 = relu(base + V*g), split hi/lo: [mt][ks]
  s8v ah[2][2], al[2][2];
  #pragma unroll
  for (int mt = 0; mt < 2; ++mt) {
    const float* vr = V + (size_t)(mt ? j1 : j0) * 64;
    #pragma unroll
    for (int ks = 0; ks < 2; ++ks) {
      int cb = ks*32 + kb*8;
      float4 v0 = *(const float4*)&vr[cb];
      float4 v1 = *(const float4*)&vr[cb + 4];
      float hv[8];
      hv[0]=base[ks][0]+v0.x*gs[ks][0]; hv[1]=base[ks][1]+v0.y*gs[ks][1];
      hv[2]=base[ks][2]+v0.z*gs[ks][2]; hv[3]=base[ks][3]+v0.w*gs[ks][3];
      hv[4]=base[ks][4]+v1.x*gs[ks][4]; hv[5]=base[ks][5]+v1.y*gs[ks][5];
      hv[6]=base[ks][6]+v1.z*gs[ks][6]; hv[7]=base[ks][7]+v1.w*gs[ks][7];
      s8v hfrag, lfrag;
      #pragma unroll
      for (int e = 0; e < 8; ++e) {
        float h1 = hv[e] > 0.f ? hv[e] : 0.f;
        u16 hh, ll;
        cvt_split(h1, hh, ll);
        hfrag[e] = (short)hh; lfrag[e] = (short)ll;
      }
      ah[mt][ks] = hfrag; al[mt][ks] = lfrag;
    }
  }

  f4v acc[2][4];
  #pragma unroll
  for (int mt = 0; mt < 2; ++mt)
    #pragma unroll
    for (int jf = 0; jf < 4; ++jf) acc[mt][jf] = (f4v)(0.f);

  #pragma unroll
  for (int mt = 0; mt < 2; ++mt)
    #pragma unroll
    for (int jf = 0; jf < 4; ++jf)
      #pragma unroll
      for (int ks = 0; ks < 2; ++ks) {
        acc[mt][jf] = __builtin_amdgcn_mfma_f32_16x16x32_bf16(ah[mt][ks], bh[jf][ks], acc[mt][jf], 0, 0, 0);
        acc[mt][jf] = __builtin_amdgcn_mfma_f32_16x16x32_bf16(ah[mt][ks], bl[jf][ks], acc[mt][jf], 0, 0, 0);
        acc[mt][jf] = __builtin_amdgcn_mfma_f32_16x16x32_bf16(al[mt][ks], bh[jf][ks], acc[mt][jf], 0, 0, 0);
      }

  // reduce: max over rows (neighbors). D row=kb*4+r, col=lr.
  #pragma unroll
  for (int jf = 0; jf < 4; ++jf) {
    float m = fmaxf(fmaxf(acc[0][jf][0], acc[0][jf][1]), fmaxf(acc[0][jf][2], acc[0][jf][3]));
    float m1 = fmaxf(fmaxf(acc[1][jf][0], acc[1][jf][1]), fmaxf(acc[1][jf][2], acc[1][jf][3]));
    m = fmaxf(m, m1);
    m = fmaxf(m, __shfl_xor(m, 16));
    m = fmaxf(m, __shfl_xor(m, 32));
    if (kb == 0) out[(size_t)p*ostride + jf*16 + lr] = m + b2[jf*16 + lr];
  }
}

// ---------------- split-bf16 MFMA GEMM: C = relu(A@W + b) ----------------
// BM=128, BN=2*NJF*16; A f32 (split in staging), W pre-split transposed [N][PKW]
template<int NJF>
__global__ __launch_bounds__(256) void k_mlp(const float* __restrict__ Ag, int lda,
    const u16* __restrict__ Wth, const u16* __restrict__ Wtl, int PKW,
    const float* __restrict__ bg,
    float* __restrict__ Cg, int ldc, int N, int K, int dorelu) {
  constexpr int PK = 40;
  __shared__ __align__(16) u16 Ah[128*PK];
  __shared__ __align__(16) u16 Al[128*PK];
  int tid  = threadIdx.x;
  int wave = tid >> 6, lane = tid & 63;
  int wm = (wave >> 1) * 64, wn = (wave & 1) * (NJF*16);
  int lr = lane & 15, kb = lane >> 4;
  int m0 = blockIdx.y * 128, n0 = blockIdx.x * (2*NJF*16);

  f4v acc[4][NJF];
  #pragma unroll
  for (int i = 0; i < 4; ++i)
    #pragma unroll
    for (int j = 0; j < NJF; ++j) acc[i][j] = (f4v)(0.f);

  for (int k0 = 0; k0 < K; k0 += 32) {
    // B fragments direct from global (L2-hot)
    s8v bh[NJF], bl[NJF];
    #pragma unroll
    for (int jf = 0; jf < NJF; ++jf) {
      int n = n0 + wn + jf*16 + lr;
      bh[jf] = *(const s8v*)&Wth[(size_t)n*PKW + k0 + kb*8];
      bl[jf] = *(const s8v*)&Wtl[(size_t)n*PKW + k0 + kb*8];
    }
    // stage A tile (f32 -> split bf16 hi/lo)
    #pragma unroll
    for (int ps = 0; ps < 4; ++ps) {
      int e4 = ps * 256 + tid;
      int r = e4 >> 3, c4 = (e4 & 7) << 2;
      float4 a = *(const float4*)&Ag[(size_t)(m0 + r)*lda + k0 + c4];
      u16 h0,h1,h2,h3,l0,l1,l2,l3;
      cvt_split(a.x, h0, l0); cvt_split(a.y, h1, l1);
      cvt_split(a.z, h2, l2); cvt_split(a.w, h3, l3);
      *(s4v*)&Ah[r*PK + c4] = s4v{(short)h0,(short)h1,(short)h2,(short)h3};
      *(s4v*)&Al[r*PK + c4] = s4v{(short)l0,(short)l1,(short)l2,(short)l3};
    }
    __syncthreads();
    #pragma unroll
    for (int mf = 0; mf < 4; ++mf) {
      int m = wm + mf*16 + lr;
      s8v ah = *(const s8v*)&Ah[m*PK + kb*8];
      s8v al = *(const s8v*)&Al[m*PK + kb*8];
      #pragma unroll
      for (int jf = 0; jf < NJF; ++jf) {
        acc[mf][jf] = __builtin_amdgcn_mfma_f32_16x16x32_bf16(ah, bh[jf], acc[mf][jf], 0, 0, 0);
        acc[mf][jf] = __builtin_amdgcn_mfma_f32_16x16x32_bf16(ah, bl[jf], acc[mf][jf], 0, 0, 0);
        acc[mf][jf] = __builtin_amdgcn_mfma_f32_16x16x32_bf16(al, bh[jf], acc[mf][jf], 0, 0, 0);
      }
    }
    __syncthreads();
  }

  #pragma unroll
  for (int jf = 0; jf < NJF; ++jf) {
    int n = n0 + wn + jf*16 + lr;
    float bb = bg[n];
    #pragma unroll
    for (int mf = 0; mf < 4; ++mf) {
      #pragma unroll
      for (int r = 0; r < 4; ++r) {
        int m = m0 + wm + mf*16 + kb*4 + r;
        float v = acc[mf][jf][r] + bb;
        if (dorelu) v = v > 0.f ? v : 0.f;
        Cg[(size_t)m*ldc + n] = v;
      }
    }
  }
}

// ---------------- head: 128->13 + log_softmax, lane per point ----------------
__global__ __launch_bounds__(256) void k_head(const float* __restrict__ H3,
    const float* __restrict__ W4, const float* __restrict__ b4,
    float* __restrict__ out0, int pbase) {
  __shared__ float w4s[128 * 13];
  __shared__ float b4s[13];
  for (int e = threadIdx.x; e < 128*13; e += 256) w4s[e] = W4[e];
  if (threadIdx.x < 13) b4s[threadIdx.x] = b4[threadIdx.x];
  __syncthreads();
  int pl = blockIdx.x * 256 + threadIdx.x;
  float acc[13];
  #pragma unroll
  for (int c = 0; c < 13; ++c) acc[c] = b4s[c];
  const float* hr = H3 + (size_t)pl * 128;
  #pragma unroll 1
  for (int k = 0; k < 128; k += 4) {
    float4 h = *(const float4*)&hr[k];
    #pragma unroll
    for (int c = 0; c < 13; ++c) {
      acc[c] += h.x * w4s[(k+0)*13 + c];
      acc[c] += h.y * w4s[(k+1)*13 + c];
      acc[c] += h.z * w4s[(k+2)*13 + c];
      acc[c] += h.w * w4s[(k+3)*13 + c];
    }
  }
  float mx = acc[0];
  #pragma unroll
  for (int c = 1; c < 13; ++c) mx = fmaxf(mx, acc[c]);
  float s = 0.f;
  #pragma unroll
  for (int c = 0; c < 13; ++c) s += expf(acc[c] - mx);
  float lg = logf(s);
  size_t ob = (size_t)(pbase + pl) * 13;
  #pragma unroll
  for (int c = 0; c < 13; ++c) out0[ob + c] = acc[c] - mx - lg;
}

// ---------------- out1 = x3 ----------------
__global__ void k_out1(const float* __restrict__ hcat, float* __restrict__ out1) {
  int e = blockIdx.x * 256 + threadIdx.x;
  int p = e >> 6, c = e & 63;
  out1[e] = hcat[(size_t)p*192 + 128 + c];
}

extern "C" void kernel_launch(void* const* d_in, const int* in_sizes, int n_in,
                              void* d_out, int out_size, void* d_ws, size_t ws_size,
                              hipStream_t stream) {
  (void)in_sizes; (void)n_in; (void)out_size; (void)ws_size;
  const float* x   = (const float*)d_in[0];
  const float* pos = (const float*)d_in[1];
  const float* cw[3][6];   // W1,b1,g,be,W2,b2 per conv
  for (int c = 0; c < 3; ++c)
    for (int t = 0; t < 6; ++t)
      cw[c][t] = (const float*)d_in[3 + c*6 + t];
  const float *mW[4], *mb[4];
  for (int j = 0; j < 4; ++j) {
    mW[j] = (const float*)d_in[21 + 2*j];
    mb[j] = (const float*)d_in[22 + 2*j];
  }

  float* ws   = (float*)d_ws;
  float* x0   = ws;                        // 131072
  float* sq   = x0 + 131072;               // 16384
  int*   knn  = (int*)(sq + 16384);        // 491520 ints
  float* A0   = (float*)(knn + 491520);    // 1048576
  float* V    = A0 + 1048576;              // 1048576
  float* hcat = V + 1048576;               // 3145728 (x1|x2|x3, stride 192)
  float* U    = hcat + 3145728;            // 8388608 (D chunks, then H1 chunk)
  float* H2c  = U + 8388608;               // 2097152
  float* H3c  = H2c + 2097152;             // 1048576
  // conv3 W2 split (hi|lo, 64x72 u16 each)
  u16* eW2 = (u16*)(H3c + 1048576);
  // MLP weight splits live in A0 region (dead after conv phase)
  u16* mwp = (u16*)A0;
  u16* m1h = mwp;            u16* m1l = m1h + 204800;   // 1024 x 200
  u16* m2h = m1l + 204800;   u16* m2l = m2h + 264192;   // 256 x 1032
  u16* m3h = m2l + 264192;   u16* m3l = m3h + 33792;    // 128 x 264

  float* out0 = (float*)d_out;
  float* out1 = out0 + 8*2048*13;

  k_build_x0<<<64, 256, 0, stream>>>(x, pos, x0);
  k_splitw<<<16, 256, 0, stream>>>(cw[2][4], 64, 64, 72, eW2, eW2 + 4608);

  for (int c = 0; c < 3; ++c) {
    const float* xin; int stride, F, Fsq;
    if (c == 0)      { xin = x0;        stride = 8;   F = 6;  Fsq = 8;  }
    else if (c == 1) { xin = hcat;      stride = 192; F = 64; Fsq = 64; }
    else             { xin = hcat + 64; stride = 192; F = 64; Fsq = 64; }
    k_sqnorm<<<4096, 256, 0, stream>>>(xin, stride, Fsq, sq);
    for (int ch = 0; ch < 4; ++ch) {
      if (c == 0) k_dist<8> <<<dim3(16,4,8), 256, 0, stream>>>(xin, stride, sq, ch*512, U);
      else        k_dist<64><<<dim3(16,4,8), 256, 0, stream>>>(xin, stride, sq, ch*512, U);
      k_topk<<<1024, 256, 0, stream>>>(U, ch*512, knn);
    }
    k_prep<<<4096, 256, 0, stream>>>(xin, stride, F, cw[c][0], cw[c][1], A0, V);
    if (c < 2)
      k_edge_v<<<4096, 256, 0, stream>>>(A0, V, knn, cw[c][4], cw[c][5],
                                         cw[c][2], cw[c][3], hcat + 64*c, 192);
    else
      k_edge_m<<<4096, 256, 0, stream>>>(A0, V, knn, eW2, eW2 + 4608,
                                         cw[c][5], cw[c][2], cw[c][3], hcat + 64*c, 192);
  }

  // split MLP weights (A0/V now dead)
  k_splitw<<<768,  256, 0, stream>>>(mW[0], 192,  1024, 200,  m1h, m1l);
  k_splitw<<<1024, 256, 0, stream>>>(mW[1], 1024, 256,  1032, m2h, m2l);
  k_splitw<<<128,  256, 0, stream>>>(mW[2], 256,  128,  264,  m3h, m3l);

  for (int ch = 0; ch < 2; ++ch) {
    const float* Ain = hcat + (size_t)ch * 8192 * 192;
    k_mlp<4><<<dim3(8,64), 256, 0, stream>>>(Ain, 192,  m1h, m1l, 200,  mb[0], U,   1024, 1024, 192,  1);
    k_mlp<2><<<dim3(4,64), 256, 0, stream>>>(U,   1024, m2h, m2l, 1032, mb[1], H2c, 256,  256,  1024, 1);
    k_mlp<2><<<dim3(2,64), 256, 0, stream>>>(H2c, 256,  m3h, m3l, 264,  mb[2], H3c, 128,  128,  256,  1);
    k_head<<<32, 256, 0, stream>>>(H3c, mW[3], mb[3], out0, ch*8192);
  }
  k_out1<<<4096, 256, 0, stream>>>(hcat, out1);
}